// Round 1
// baseline (236.037 us; speedup 1.0000x reference)
//
#include <hip/hip_runtime.h>

#define BSZ   32
#define SEQ   64
#define HID   256
#define G4    1024
#define NSTEP 64

typedef unsigned long long u64;
typedef unsigned int       u32;

__device__ __forceinline__ float sigmoidf_(float v) { return 1.f / (1.f + __expf(-v)); }

// ---------------------------------------------------------------------------
// Kernel 1: context[b,j] = sum_s softmax_s(x @ Wa_x)[b,s,j] * x[b,s,j]
// (ht/ct/ba terms in the reference are constant along the softmax axis and
//  cancel exactly — softmax shift invariance.)
// grid: 32 b * 8 jt = 256 blocks; block: 256 threads = (j in 32) x (so in 8)
// thread = j*8+so covers s = so*8 .. so*8+7  -> shfl_xor(1,2,4) reduces over s
// ---------------------------------------------------------------------------
__global__ __launch_bounds__(256) void k_context(
    const float* __restrict__ x, const float* __restrict__ Wa,
    float* __restrict__ ctx)
{
  const int b   = blockIdx.x >> 3;
  const int jt  = blockIdx.x & 7;
  const int j   = threadIdx.x >> 3;
  const int so  = threadIdx.x & 7;
  const int jch = jt * 32 + j;
  const float* xb = x + (size_t)b * SEQ * HID;

  float acc[8];
#pragma unroll
  for (int i = 0; i < 8; ++i) acc[i] = 0.f;

  for (int k4 = 0; k4 < HID / 4; ++k4) {
    float4 xv[8];
#pragma unroll
    for (int ss = 0; ss < 8; ++ss)
      xv[ss] = *(const float4*)(xb + (so * 8 + ss) * HID + k4 * 4);
    const float wa0 = Wa[(k4 * 4 + 0) * HID + jch];
    const float wa1 = Wa[(k4 * 4 + 1) * HID + jch];
    const float wa2 = Wa[(k4 * 4 + 2) * HID + jch];
    const float wa3 = Wa[(k4 * 4 + 3) * HID + jch];
#pragma unroll
    for (int ss = 0; ss < 8; ++ss) {
      acc[ss] += xv[ss].x * wa0;
      acc[ss] += xv[ss].y * wa1;
      acc[ss] += xv[ss].z * wa2;
      acc[ss] += xv[ss].w * wa3;
    }
  }

  // softmax over the 64 s for this (b, jch): local 8 + shfl over so-partners
  float m = acc[0];
#pragma unroll
  for (int ss = 1; ss < 8; ++ss) m = fmaxf(m, acc[ss]);
  m = fmaxf(m, __shfl_xor(m, 1));
  m = fmaxf(m, __shfl_xor(m, 2));
  m = fmaxf(m, __shfl_xor(m, 4));

  float e[8], s_ = 0.f;
#pragma unroll
  for (int ss = 0; ss < 8; ++ss) { e[ss] = __expf(acc[ss] - m); s_ += e[ss]; }
  s_ += __shfl_xor(s_, 1);
  s_ += __shfl_xor(s_, 2);
  s_ += __shfl_xor(s_, 4);
  const float inv = 1.f / s_;

  float cx = 0.f;
#pragma unroll
  for (int ss = 0; ss < 8; ++ss)
    cx += e[ss] * xb[(so * 8 + ss) * HID + jch];
  cx *= inv;
  cx += __shfl_xor(cx, 1);
  cx += __shfl_xor(cx, 2);
  cx += __shfl_xor(cx, 4);

  if (so == 0) ctx[b * HID + jch] = cx;
}

// ---------------------------------------------------------------------------
// Kernel 2: 64 sequential LSTM steps. grid: 32 b * 8 q = 256 blocks.
// Block (b,q) owns hidden j in [q*32, q*32+32) => 128 Wh columns
// ({i,f,g,o} x 32), held in VGPRs (wh[32] float4 per thread).
// Thread = (cg in 32) x (kq in 8): 4 consecutive cols, k-slice kq*32..+32.
// ht exchange between the 8 sibling blocks: tagged 8B words in d_ws
// (hi32 = f32 value, lo32 = step tag), relaxed agent-scope atomics,
// double-buffered by step parity. Poison 0xAAAAAAAA never matches tags 1..64.
// ---------------------------------------------------------------------------
__global__ __launch_bounds__(256, 1) void k_recurrent(
    const float* __restrict__ Wi, const float* __restrict__ Wh,
    const float* __restrict__ bias, const float* __restrict__ Wf,
    const float* __restrict__ bf, const float* __restrict__ ctx,
    u64* __restrict__ tht, float* __restrict__ out)
{
  const int b   = blockIdx.x >> 3;
  const int q   = blockIdx.x & 7;
  const int tid = threadIdx.x;
  const int cg  = tid >> 3;
  const int kq  = tid & 7;
  // col0: gate (cg>>3), hidden j = q*32 + (cg&7)*4 .. +3
  const int col0 = (cg >> 3) * HID + q * 32 + (cg & 7) * 4;

  __shared__ float hs[2][8][36];  // [parity][kq][32 k + pad]; 144B rows keep f4 alignment
  __shared__ float gs[128];       // gates for this block's 128 cols (lc = g*32+jj)

  // ---- Wh slice -> registers (one-time) ----
  float4 wh[32];
#pragma unroll
  for (int kk = 0; kk < 32; ++kk)
    wh[kk] = *(const float4*)(Wh + (size_t)(kq * 32 + kk) * G4 + col0);

  // ---- stage context into hs[0] ----
  hs[0][tid >> 5][tid & 31] = ctx[b * HID + tid];
  __syncthreads();

  // ---- Gc = ctx @ Wi + bias for this block's columns ----
  float gx = 0.f, gy = 0.f, gz = 0.f, gw = 0.f;
#pragma unroll 4
  for (int kk = 0; kk < 32; ++kk) {
    const float4 wv = *(const float4*)(Wi + (size_t)(kq * 32 + kk) * G4 + col0);
    const float h = hs[0][kq][kk];
    gx += h * wv.x; gy += h * wv.y; gz += h * wv.z; gw += h * wv.w;
  }
#pragma unroll
  for (int mk = 1; mk < 8; mk <<= 1) {
    gx += __shfl_xor(gx, mk); gy += __shfl_xor(gy, mk);
    gz += __shfl_xor(gz, mk); gw += __shfl_xor(gw, mk);
  }
  float gcx, gcy, gcz, gcw;
  if (kq == 0) {
    const float4 bb = *(const float4*)(bias + col0);
    gcx = gx + bb.x; gcy = gy + bb.y; gcz = gz + bb.z; gcw = gw + bb.w;
  } else {
    gcx = gcy = gcz = gcw = 0.f;  // only kq==0 seeds the reduction with Gc
  }
  __syncthreads();
  hs[0][tid >> 5][tid & 31] = 0.f;  // h0 = 0
  float ct = 0.f;                   // c state lives in threads tid<32
  __syncthreads();

  for (int t = 0; t < NSTEP; ++t) {
    const int rb = t & 1;
    const int wb = (t + 1) & 1;

    if (t > 0) {
      // poll full ht (incl. our own slice) for tag == t, stage into LDS
      const u64* p = tht + (size_t)rb * BSZ * HID + (size_t)b * HID + tid;
      u64 pk;
      do {
        pk = __hip_atomic_load(p, __ATOMIC_RELAXED, __HIP_MEMORY_SCOPE_AGENT);
      } while ((u32)pk != (u32)t);
      hs[rb][tid >> 5][tid & 31] = __uint_as_float((u32)(pk >> 32));
      __syncthreads();
    }

    // gates partial: 4 cols x 32 k per thread, Wh from registers
    float ax = gcx, ay = gcy, az = gcz, aw = gcw;
#pragma unroll
    for (int k4 = 0; k4 < 8; ++k4) {
      const float4 h4 = *(const float4*)&hs[rb][kq][k4 * 4];
#pragma unroll
      for (int e2 = 0; e2 < 4; ++e2) {
        const float h = (e2 == 0) ? h4.x : (e2 == 1) ? h4.y : (e2 == 2) ? h4.z : h4.w;
        const float4 w = wh[k4 * 4 + e2];
        ax += h * w.x; ay += h * w.y; az += h * w.z; aw += h * w.w;
      }
    }
    // reduce over the 8 kq partners (adjacent lanes)
#pragma unroll
    for (int mk = 1; mk < 8; mk <<= 1) {
      ax += __shfl_xor(ax, mk); ay += __shfl_xor(ay, mk);
      az += __shfl_xor(az, mk); aw += __shfl_xor(aw, mk);
    }
    if (kq == 0) {
      gs[cg * 4 + 0] = ax; gs[cg * 4 + 1] = ay;
      gs[cg * 4 + 2] = az; gs[cg * 4 + 3] = aw;
    }
    __syncthreads();

    // LSTM pointwise for our 32 hidden units; publish tagged ht
    if (tid < 32) {
      const float gi = gs[tid], gf = gs[32 + tid], gg = gs[64 + tid], go = gs[96 + tid];
      const float ig = sigmoidf_(gi);
      const float fg = sigmoidf_(gf);
      const float g2 = tanhf(gg);
      const float og = sigmoidf_(go);
      ct = fg * ct + ig * g2;
      const float hv = og * tanhf(ct);
      const u64 pk = (((u64)__float_as_uint(hv)) << 32) | (u64)(u32)(t + 1);
      __hip_atomic_store(tht + (size_t)wb * BSZ * HID + (size_t)b * HID + q * 32 + tid,
                         pk, __ATOMIC_RELAXED, __HIP_MEMORY_SCOPE_AGENT);
    }
    // no barrier needed here: next iteration's staging targets the other
    // parity buffer, and gs is rewritten only after the next __syncthreads
  }

  // ---- epilogue: out[b] = ht64 @ Wf + bf, done by the q==0 sibling ----
  if (q == 0) {
    const u64* p = tht + /*parity 0*/ (size_t)b * HID + tid;
    u64 pk;
    do {
      pk = __hip_atomic_load(p, __ATOMIC_RELAXED, __HIP_MEMORY_SCOPE_AGENT);
    } while ((u32)pk != (u32)NSTEP);
    const float hv = __uint_as_float((u32)(pk >> 32));
    float prod = hv * Wf[tid];
#pragma unroll
    for (int mk = 1; mk < 64; mk <<= 1) prod += __shfl_xor(prod, mk);
    __syncthreads();   // gs reuse is safe: everyone is past the step loop
    if ((tid & 63) == 0) gs[tid >> 6] = prod;
    __syncthreads();
    if (tid == 0) out[b] = gs[0] + gs[1] + gs[2] + gs[3] + bf[0];
  }
}

// ---------------------------------------------------------------------------
extern "C" void kernel_launch(void* const* d_in, const int* in_sizes, int n_in,
                              void* d_out, int out_size, void* d_ws, size_t ws_size,
                              hipStream_t stream)
{
  const float* x  = (const float*)d_in[0];
  const float* Wa = (const float*)d_in[1];
  // d_in[2] = ba: unused — constant along softmax axis, cancels exactly
  const float* Wi = (const float*)d_in[3];
  const float* Wh = (const float*)d_in[4];
  const float* bi = (const float*)d_in[5];
  const float* Wf = (const float*)d_in[6];
  const float* bf = (const float*)d_in[7];
  float* out = (float*)d_out;

  // ws layout: [0,32KB) fp32 context; [32KB, 32KB+128KB) tagged ht (2 parity bufs)
  float* ctx = (float*)d_ws;
  u64*   tht = (u64*)((char*)d_ws + 32 * 1024);

  hipLaunchKernelGGL(k_context,   dim3(BSZ * 8), dim3(256), 0, stream, x, Wa, ctx);
  hipLaunchKernelGGL(k_recurrent, dim3(BSZ * 8), dim3(256), 0, stream,
                     Wi, Wh, bi, Wf, bf, ctx, tht, out);
}